// Round 5
// baseline (550.732 us; speedup 1.0000x reference)
//
#include <hip/hip_runtime.h>
#include <hip/hip_bf16.h>

#define NNODES 40000
#define MPAD   40064   // 313 * 128
#define NEDGES 640000
#define FIN    128
#define HID    512
#define NGRAPH 64

typedef __attribute__((ext_vector_type(8))) short bf16x8;
typedef __attribute__((ext_vector_type(4))) float f32x4;

__device__ __forceinline__ unsigned short f2bf(float f) {
    unsigned int u = __builtin_bit_cast(unsigned int, f);
    u += 0x7FFFu + ((u >> 16) & 1u);   // RNE
    return (unsigned short)(u >> 16);
}
__device__ __forceinline__ float bf2f(unsigned short s) {
    return __builtin_bit_cast(float, (unsigned int)s << 16);
}

__device__ __forceinline__ void gload_lds16(const void* g, void* l) {
    __builtin_amdgcn_global_load_lds(
        (const __attribute__((address_space(1))) void*)g,
        (__attribute__((address_space(3))) void*)l, 16, 0, 0);
}

// ---------------- conversions ----------------

__global__ void k_cvt_x(const float* __restrict__ x, unsigned short* __restrict__ xb) {
    size_t e = ((size_t)blockIdx.x * 256 + threadIdx.x) * 8;
    if (e >= (size_t)MPAD * FIN) return;
    bf16x8 o;
    if (e < (size_t)NNODES * FIN) {
        float4 v0 = *(const float4*)(x + e);
        float4 v1 = *(const float4*)(x + e + 4);
        o[0] = f2bf(v0.x); o[1] = f2bf(v0.y); o[2] = f2bf(v0.z); o[3] = f2bf(v0.w);
        o[4] = f2bf(v1.x); o[5] = f2bf(v1.y); o[6] = f2bf(v1.z); o[7] = f2bf(v1.w);
    } else {
        o = (bf16x8)0;
    }
    *(bf16x8*)(xb + e) = o;
}

__global__ void k_cvt_wt(const float* __restrict__ W, unsigned short* __restrict__ Wt, int K) {
    int t = blockIdx.x * 256 + threadIdx.x;
    if (t >= 512 * K) return;
    int n = t / K, k = t - n * K;
    Wt[t] = f2bf(W[(size_t)k * 512 + n]);
}

// ---------------- CSR build ----------------

__global__ void k_deg(const int* __restrict__ dst, int* __restrict__ deg) {
    int e = blockIdx.x * 256 + threadIdx.x;
    if (e < NEDGES) atomicAdd(&deg[dst[e]], 1);
}

__global__ void k_scan(const int* __restrict__ deg, int* __restrict__ off, int* __restrict__ cursor) {
    __shared__ int sh[1024];
    constexpr int CH = (NNODES + 1023) / 1024;
    int t = threadIdx.x;
    int base = t * CH;
    int vals[CH];
    int local = 0;
#pragma unroll
    for (int i = 0; i < CH; ++i) {
        int idx = base + i;
        int v = (idx < NNODES) ? deg[idx] : 0;
        vals[i] = v;
        local += v;
    }
    sh[t] = local;
    __syncthreads();
    for (int o = 1; o < 1024; o <<= 1) {
        int add = (t >= o) ? sh[t - o] : 0;
        __syncthreads();
        sh[t] += add;
        __syncthreads();
    }
    int run = sh[t] - local;
#pragma unroll
    for (int i = 0; i < CH; ++i) {
        int idx = base + i;
        if (idx < NNODES) {
            off[idx] = run;
            cursor[idx] = run;
            run += vals[i];
        }
    }
    if (t == 1023) off[NNODES] = sh[1023];
}

__global__ void k_fill(const int* __restrict__ src, const int* __restrict__ dst,
                       const float* __restrict__ ew, int* __restrict__ cursor,
                       int* __restrict__ csrc, float* __restrict__ cw) {
    int e = blockIdx.x * 256 + threadIdx.x;
    if (e < NEDGES) {
        int p = atomicAdd(&cursor[dst[e]], 1);
        csrc[p] = src[e];
        cw[p] = ew[e];
    }
}

// ---------------- aggregation (gather, bf16 in/out, fp32 accum) ----------------

__global__ void k_agg128(const unsigned short* __restrict__ xb, const int* __restrict__ off,
                         const int* __restrict__ csrc, const float* __restrict__ cw,
                         unsigned short* __restrict__ out) {
    int node = blockIdx.x * 4 + (threadIdx.x >> 6);
    if (node >= NNODES) return;
    int lane = threadIdx.x & 63;
    float a0 = 0.f, a1 = 0.f;
    int s = off[node], e = off[node + 1];
    for (int k = s; k < e; ++k) {
        int j = csrc[k];
        float w = cw[k];
        unsigned int v = *(const unsigned int*)(xb + (size_t)j * FIN + lane * 2);
        a0 += w * bf2f((unsigned short)(v & 0xFFFF));
        a1 += w * bf2f((unsigned short)(v >> 16));
    }
    unsigned int o = (unsigned int)f2bf(a0) | ((unsigned int)f2bf(a1) << 16);
    *(unsigned int*)(out + (size_t)node * FIN + lane * 2) = o;
}

__global__ void k_agg512(const unsigned short* __restrict__ h, const int* __restrict__ off,
                         const int* __restrict__ csrc, const float* __restrict__ cw,
                         unsigned short* __restrict__ out) {
    int node = blockIdx.x * 4 + (threadIdx.x >> 6);
    if (node >= NNODES) return;
    int lane = threadIdx.x & 63;
    float acc[8] = {};
    int s = off[node], e = off[node + 1];
    for (int k = s; k < e; ++k) {
        int j = csrc[k];
        float w = cw[k];
        bf16x8 a = *(const bf16x8*)(h + (size_t)j * HID + lane * 8);
#pragma unroll
        for (int q = 0; q < 8; ++q)
            acc[q] += w * bf2f((unsigned short)a[q]);
    }
    bf16x8 o;
#pragma unroll
    for (int q = 0; q < 8; ++q) o[q] = (short)f2bf(acc[q]);
    *(bf16x8*)(out + (size_t)node * HID + lane * 8) = o;
}

// ---------------- dual MFMA GEMM: C = relu(A0@B0 + A1@B1 + bias) ----------------
// A: [MPAD][K] bf16; Bt: [512][K] bf16 (pre-transposed). 128x128 tile, BK=32,
// 4 waves (2x2 of 64x64), 4x4 16x16x32 frags/wave.
// T4 counted-vmcnt pipeline, 3-deep LDS buffers:
//   prologue: stage(0), stage(1)
//   iter t:   s_waitcnt vmcnt(4)  (oldest stage landed, newest 4 loads stay
//             in flight)  ->  s_barrier  ->  stage(t+2)  ->  ds_read+MFMA
//   last iter peeled with vmcnt(0). Never drain vmcnt mid-loop (T4).
// Hazards: stage(t+2) overwrites the buffer read at iter t-1; those reads are
// sealed by barrier t (reads precede it, data consumed by MFMA before it).
// Stage visibility: each wave waits its OWN vmcnt before the shared barrier.
// LDS k-slot XOR-swizzle p = s ^ ((row>>1)&3) applied BOTH on the per-lane
// global source (linear gload_lds dest) and the ds_read index (rule #21).
// Bijective XCD chunk swizzle (T1/m204): each XCD owns consecutive logical
// tiles -> 4 col-blocks sharing an A panel hit the same XCD L2.

template <int K, bool POOL>
__global__ __launch_bounds__(256)
void k_mfma_dual(const unsigned short* __restrict__ A0, const unsigned short* __restrict__ B0t,
                 const unsigned short* __restrict__ A1, const unsigned short* __restrict__ B1t,
                 const float* __restrict__ bias,
                 unsigned short* __restrict__ C,
                 const int* __restrict__ batch, float* __restrict__ psum) {
    constexpr int KT = K / 32;       // K-tiles per matrix
    constexpr int NT = 2 * KT;       // total tiles (two matrices), >= 8
    __shared__ unsigned short As[3][128 * 32];
    __shared__ unsigned short Bs[3][128 * 32];
    int tid = threadIdx.x;
    int l = tid & 63, w = tid >> 6;
    int wr = w >> 1, wc = w & 1;

    // bijective XCD chunking: orig -> logical wgid, contiguous chunk per XCD
    int nwg = gridDim.x;
    int orig = blockIdx.x;
    int q = nwg >> 3, r = nwg & 7;
    int xcd = orig & 7, idx = orig >> 3;
    int wgid = (xcd < r ? xcd * (q + 1) : r * (q + 1) + (xcd - r) * q) + idx;
    int row0 = (wgid >> 2) * 128;
    int col0 = (wgid & 3) * 128;

    int lr = l & 15, hi = l >> 4;
    int pofs = (hi ^ ((lr >> 1) & 3)) * 8;   // swizzled k-slot offset (ushorts)

    // staging chunk geometry: chunk c in [0,512), r=c>>2, p=c&3,
    // global slot g = p ^ ((r>>1)&3); LDS dest linear at c*16 bytes.
    int c0 = tid, c1 = tid + 256;
    int r0 = c0 >> 2, g0 = (c0 & 3) ^ ((r0 >> 1) & 3);
    int r1 = c1 >> 2, g1 = (c1 & 3) ^ ((r1 >> 1) & 3);

    const unsigned short* Amat[2] = {A0, A1};
    const unsigned short* Bmat[2] = {B0t, B1t};

    auto stage = [&](int t, int buf) {
        int mat = t / KT;
        int k0 = (t - mat * KT) * 32;
        const unsigned short* A = Amat[mat];
        const unsigned short* Bt = Bmat[mat];
        gload_lds16(A + (size_t)(row0 + r0) * K + k0 + g0 * 8, &As[buf][c0 * 8]);
        gload_lds16(A + (size_t)(row0 + r1) * K + k0 + g1 * 8, &As[buf][c1 * 8]);
        gload_lds16(Bt + (size_t)(col0 + r0) * K + k0 + g0 * 8, &Bs[buf][c0 * 8]);
        gload_lds16(Bt + (size_t)(col0 + r1) * K + k0 + g1 * 8, &Bs[buf][c1 * 8]);
    };

    f32x4 acc[4][4];
#pragma unroll
    for (int m = 0; m < 4; ++m)
#pragma unroll
        for (int n = 0; n < 4; ++n) acc[m][n] = (f32x4)0.f;

    stage(0, 0);
    stage(1, 1);

    auto compute = [&](int buf) {
        const unsigned short* Ab = &As[buf][0];
        const unsigned short* Bb = &Bs[buf][0];
        bf16x8 af[4], bfr[4];
#pragma unroll
        for (int m = 0; m < 4; ++m)
            af[m] = *(const bf16x8*)&Ab[(wr * 64 + m * 16 + lr) * 32 + pofs];
#pragma unroll
        for (int n = 0; n < 4; ++n)
            bfr[n] = *(const bf16x8*)&Bb[(wc * 64 + n * 16 + lr) * 32 + pofs];
#pragma unroll
        for (int m = 0; m < 4; ++m)
#pragma unroll
            for (int n = 0; n < 4; ++n)
                acc[m][n] = __builtin_amdgcn_mfma_f32_16x16x32_bf16(af[m], bfr[n], acc[m][n], 0, 0, 0);
    };

    for (int t = 0; t < NT - 1; ++t) {
        asm volatile("s_waitcnt vmcnt(4)" ::: "memory");  // oldest stage landed
        __builtin_amdgcn_s_barrier();
        __builtin_amdgcn_sched_barrier(0);
        if (t + 2 < NT) stage(t + 2, (t + 2) % 3);
        compute(t % 3);
    }
    // peeled last iteration: drain everything
    asm volatile("s_waitcnt vmcnt(0)" ::: "memory");
    __builtin_amdgcn_s_barrier();
    __builtin_amdgcn_sched_barrier(0);
    compute((NT - 1) % 3);

    // epilogue: C/D layout col = l&15, row = (l>>4)*4 + i
    float bv[4];
#pragma unroll
    for (int n = 0; n < 4; ++n) bv[n] = bias[col0 + wc * 64 + n * 16 + lr];
    int rbase = row0 + wr * 64 + hi * 4;

    if constexpr (!POOL) {
#pragma unroll
        for (int m = 0; m < 4; ++m) {
#pragma unroll
            for (int i = 0; i < 4; ++i) {
                int rr = rbase + m * 16 + i;
                if (rr < NNODES) {
#pragma unroll
                    for (int n = 0; n < 4; ++n) {
                        int col = col0 + wc * 64 + n * 16 + lr;
                        C[(size_t)rr * HID + col] = f2bf(fmaxf(acc[m][n][i] + bv[n], 0.f));
                    }
                }
            }
        }
    } else {
#pragma unroll
        for (int m = 0; m < 4; ++m) {
            int b[4];
#pragma unroll
            for (int i = 0; i < 4; ++i) {
                int rr = rbase + m * 16 + i;
                b[i] = (rr < NNODES) ? batch[rr] : -1;
            }
#pragma unroll
            for (int n = 0; n < 4; ++n) {
                int col = col0 + wc * 64 + n * 16 + lr;
                int cb = -1;
                float run = 0.f;
#pragma unroll
                for (int i = 0; i < 4; ++i) {
                    if (b[i] >= 0) {
                        float v = fmaxf(acc[m][n][i] + bv[n], 0.f);
                        if (b[i] == cb) {
                            run += v;
                        } else {
                            if (cb >= 0) atomicAdd(&psum[(size_t)cb * HID + col], run);
                            cb = b[i];
                            run = v;
                        }
                    }
                }
                if (cb >= 0) atomicAdd(&psum[(size_t)cb * HID + col], run);
            }
        }
    }
}

// ---------------- pooling count (LDS histogram) + MLP head (fp32) ----------------

__global__ void k_cnt(const int* __restrict__ batch, float* __restrict__ cnt) {
    __shared__ int h[NGRAPH];
    int t = threadIdx.x;
    if (t < NGRAPH) h[t] = 0;
    __syncthreads();
    int i = blockIdx.x * 256 + t;
    if (i < NNODES) atomicAdd(&h[batch[i]], 1);
    __syncthreads();
    if (t < NGRAPH && h[t] != 0) atomicAdd(&cnt[t], (float)h[t]);
}

__global__ void k_head(const float* __restrict__ psum, const float* __restrict__ cnt,
                       const float* __restrict__ W1, const float* __restrict__ b1,
                       const float* __restrict__ W2, const float* __restrict__ b2,
                       const float* __restrict__ W3, const float* __restrict__ b3,
                       float* __restrict__ out) {
    __shared__ float pooled[HID];
    __shared__ float o1[64];
    __shared__ float o2[16];
    int g = blockIdx.x, t = threadIdx.x;
    float c = fmaxf(cnt[g], 1.0f);
    for (int k = t; k < HID; k += 64) pooled[k] = psum[(size_t)g * HID + k] / c;
    __syncthreads();
    float a = b1[t];
    for (int k = 0; k < HID; ++k) a += pooled[k] * W1[k * 64 + t];
    o1[t] = fmaxf(a, 0.f);
    __syncthreads();
    if (t < 16) {
        float a2 = b2[t];
        for (int k = 0; k < 64; ++k) a2 += o1[k] * W2[k * 16 + t];
        o2[t] = fmaxf(a2, 0.f);
    }
    __syncthreads();
    if (t == 0) {
        float a3 = b3[0];
        for (int k = 0; k < 16; ++k) a3 += o2[k] * W3[k];
        out[g] = a3;
    }
}

// ---------------- launch ----------------

extern "C" void kernel_launch(void* const* d_in, const int* in_sizes, int n_in,
                              void* d_out, int out_size, void* d_ws, size_t ws_size,
                              hipStream_t stream) {
    const float* x = (const float*)d_in[0];
    const int* ei = (const int*)d_in[1];
    const int* src = ei;
    const int* dst = ei + NEDGES;
    const float* ew = (const float*)d_in[2];
    const int* batch = (const int*)d_in[3];
    const float* Wr1 = (const float*)d_in[4];
    const float* br1 = (const float*)d_in[5];
    const float* Wo1 = (const float*)d_in[6];
    const float* Wr2 = (const float*)d_in[7];
    const float* br2 = (const float*)d_in[8];
    const float* Wo2 = (const float*)d_in[9];
    const float* W1 = (const float*)d_in[10];
    const float* b1 = (const float*)d_in[11];
    const float* W2 = (const float*)d_in[12];
    const float* b2 = (const float*)d_in[13];
    const float* W3 = (const float*)d_in[14];
    const float* b3 = (const float*)d_in[15];
    float* out = (float*)d_out;

    char* ws = (char*)d_ws;
    size_t o = 0;
    auto alloc = [&](size_t bytes) -> void* {
        void* p = ws + o;
        o = (o + bytes + 255) & ~(size_t)255;
        return p;
    };
    int* deg = (int*)alloc((size_t)NNODES * 4);
    int* off = (int*)alloc((size_t)(NNODES + 1) * 4);
    int* cur = (int*)alloc((size_t)NNODES * 4);
    int* csrc = (int*)alloc((size_t)NEDGES * 4);
    float* cw = (float*)alloc((size_t)NEDGES * 4);
    unsigned short* xb = (unsigned short*)alloc((size_t)MPAD * FIN * 2);
    unsigned short* agg1 = (unsigned short*)alloc((size_t)MPAD * FIN * 2);
    unsigned short* h1 = (unsigned short*)alloc((size_t)MPAD * HID * 2);
    unsigned short* agg2 = (unsigned short*)alloc((size_t)MPAD * HID * 2);
    unsigned short* Wr1t = (unsigned short*)alloc((size_t)512 * FIN * 2);
    unsigned short* Wo1t = (unsigned short*)alloc((size_t)512 * FIN * 2);
    unsigned short* Wr2t = (unsigned short*)alloc((size_t)512 * HID * 2);
    unsigned short* Wo2t = (unsigned short*)alloc((size_t)512 * HID * 2);
    float* psum = (float*)alloc((size_t)NGRAPH * HID * 4);
    float* cnt = (float*)alloc((size_t)NGRAPH * 4);

    hipMemsetAsync(deg, 0, (size_t)NNODES * 4, stream);
    hipMemsetAsync(psum, 0, (size_t)NGRAPH * HID * 4, stream);
    hipMemsetAsync(cnt, 0, (size_t)NGRAPH * 4, stream);

    // conversions
    k_cvt_x<<<(MPAD * FIN / 8 + 255) / 256, 256, 0, stream>>>(x, xb);
    k_cvt_wt<<<(512 * FIN + 255) / 256, 256, 0, stream>>>(Wr1, Wr1t, FIN);
    k_cvt_wt<<<(512 * FIN + 255) / 256, 256, 0, stream>>>(Wo1, Wo1t, FIN);
    k_cvt_wt<<<(512 * HID + 255) / 256, 256, 0, stream>>>(Wr2, Wr2t, HID);
    k_cvt_wt<<<(512 * HID + 255) / 256, 256, 0, stream>>>(Wo2, Wo2t, HID);

    // CSR
    k_deg<<<(NEDGES + 255) / 256, 256, 0, stream>>>(dst, deg);
    k_scan<<<1, 1024, 0, stream>>>(deg, off, cur);
    k_fill<<<(NEDGES + 255) / 256, 256, 0, stream>>>(src, dst, ew, cur, csrc, cw);

    // layer 1
    k_agg128<<<(NNODES + 3) / 4, 256, 0, stream>>>(xb, off, csrc, cw, agg1);
    int nblk = (MPAD / 128) * 4;   // col in low 2 bits of logical id
    k_mfma_dual<FIN, false><<<nblk, 256, 0, stream>>>(agg1, Wr1t, xb, Wo1t, br1, h1, nullptr, nullptr);

    // layer 2 (+ fused mean-pool numerator)
    k_agg512<<<(NNODES + 3) / 4, 256, 0, stream>>>(h1, off, csrc, cw, agg2);
    k_cnt<<<(NNODES + 255) / 256, 256, 0, stream>>>(batch, cnt);
    k_mfma_dual<HID, true><<<nblk, 256, 0, stream>>>(agg2, Wr2t, h1, Wo2t, br2, nullptr, batch, psum);

    // head
    k_head<<<NGRAPH, 64, 0, stream>>>(psum, cnt, W1, b1, W2, b2, W3, b3, out);
}

// Round 6
// 542.930 us; speedup vs baseline: 1.0144x; 1.0144x over previous
//
#include <hip/hip_runtime.h>
#include <hip/hip_bf16.h>

#define NNODES 40000
#define MPAD   40064   // 313 * 128
#define NEDGES 640000
#define FIN    128
#define HID    512
#define NGRAPH 64

typedef __attribute__((ext_vector_type(8))) short bf16x8;
typedef __attribute__((ext_vector_type(4))) float f32x4;

__device__ __forceinline__ unsigned short f2bf(float f) {
    unsigned int u = __builtin_bit_cast(unsigned int, f);
    u += 0x7FFFu + ((u >> 16) & 1u);   // RNE
    return (unsigned short)(u >> 16);
}
__device__ __forceinline__ float bf2f(unsigned short s) {
    return __builtin_bit_cast(float, (unsigned int)s << 16);
}

__device__ __forceinline__ void gload_lds16(const void* g, void* l) {
    __builtin_amdgcn_global_load_lds(
        (const __attribute__((address_space(1))) void*)g,
        (__attribute__((address_space(3))) void*)l, 16, 0, 0);
}

// ---------------- conversions ----------------

__global__ void k_cvt_x(const float* __restrict__ x, unsigned short* __restrict__ xb) {
    size_t e = ((size_t)blockIdx.x * 256 + threadIdx.x) * 8;
    if (e >= (size_t)MPAD * FIN) return;
    bf16x8 o;
    if (e < (size_t)NNODES * FIN) {
        float4 v0 = *(const float4*)(x + e);
        float4 v1 = *(const float4*)(x + e + 4);
        o[0] = f2bf(v0.x); o[1] = f2bf(v0.y); o[2] = f2bf(v0.z); o[3] = f2bf(v0.w);
        o[4] = f2bf(v1.x); o[5] = f2bf(v1.y); o[6] = f2bf(v1.z); o[7] = f2bf(v1.w);
    } else {
        o = (bf16x8)0;
    }
    *(bf16x8*)(xb + e) = o;
}

__global__ void k_cvt_wt(const float* __restrict__ W, unsigned short* __restrict__ Wt, int K) {
    int t = blockIdx.x * 256 + threadIdx.x;
    if (t >= 512 * K) return;
    int n = t / K, k = t - n * K;
    Wt[t] = f2bf(W[(size_t)k * 512 + n]);
}

// ---------------- CSR build ----------------

__global__ void k_deg(const int* __restrict__ dst, int* __restrict__ deg) {
    int e = blockIdx.x * 256 + threadIdx.x;
    if (e < NEDGES) atomicAdd(&deg[dst[e]], 1);
}

__global__ void k_scan(const int* __restrict__ deg, int* __restrict__ off, int* __restrict__ cursor) {
    __shared__ int sh[1024];
    constexpr int CH = (NNODES + 1023) / 1024;
    int t = threadIdx.x;
    int base = t * CH;
    int vals[CH];
    int local = 0;
#pragma unroll
    for (int i = 0; i < CH; ++i) {
        int idx = base + i;
        int v = (idx < NNODES) ? deg[idx] : 0;
        vals[i] = v;
        local += v;
    }
    sh[t] = local;
    __syncthreads();
    for (int o = 1; o < 1024; o <<= 1) {
        int add = (t >= o) ? sh[t - o] : 0;
        __syncthreads();
        sh[t] += add;
        __syncthreads();
    }
    int run = sh[t] - local;
#pragma unroll
    for (int i = 0; i < CH; ++i) {
        int idx = base + i;
        if (idx < NNODES) {
            off[idx] = run;
            cursor[idx] = run;
            run += vals[i];
        }
    }
    if (t == 1023) off[NNODES] = sh[1023];
}

__global__ void k_fill(const int* __restrict__ src, const int* __restrict__ dst,
                       const float* __restrict__ ew, int* __restrict__ cursor,
                       int* __restrict__ csrc, float* __restrict__ cw) {
    int e = blockIdx.x * 256 + threadIdx.x;
    if (e < NEDGES) {
        int p = atomicAdd(&cursor[dst[e]], 1);
        csrc[p] = src[e];
        cw[p] = ew[e];
    }
}

// ---------------- aggregation (gather, bf16 in/out, fp32 accum) ----------------

__global__ void k_agg128(const unsigned short* __restrict__ xb, const int* __restrict__ off,
                         const int* __restrict__ csrc, const float* __restrict__ cw,
                         unsigned short* __restrict__ out) {
    int node = blockIdx.x * 4 + (threadIdx.x >> 6);
    if (node >= NNODES) return;
    int lane = threadIdx.x & 63;
    float a0 = 0.f, a1 = 0.f;
    int s = off[node], e = off[node + 1];
    for (int k = s; k < e; ++k) {
        int j = csrc[k];
        float w = cw[k];
        unsigned int v = *(const unsigned int*)(xb + (size_t)j * FIN + lane * 2);
        a0 += w * bf2f((unsigned short)(v & 0xFFFF));
        a1 += w * bf2f((unsigned short)(v >> 16));
    }
    unsigned int o = (unsigned int)f2bf(a0) | ((unsigned int)f2bf(a1) << 16);
    *(unsigned int*)(out + (size_t)node * FIN + lane * 2) = o;
}

__global__ void k_agg512(const unsigned short* __restrict__ h, const int* __restrict__ off,
                         const int* __restrict__ csrc, const float* __restrict__ cw,
                         unsigned short* __restrict__ out) {
    int node = blockIdx.x * 4 + (threadIdx.x >> 6);
    if (node >= NNODES) return;
    int lane = threadIdx.x & 63;
    float acc[8] = {};
    int s = off[node], e = off[node + 1];
    for (int k = s; k < e; ++k) {
        int j = csrc[k];
        float w = cw[k];
        bf16x8 a = *(const bf16x8*)(h + (size_t)j * HID + lane * 8);
#pragma unroll
        for (int q = 0; q < 8; ++q)
            acc[q] += w * bf2f((unsigned short)a[q]);
    }
    bf16x8 o;
#pragma unroll
    for (int q = 0; q < 8; ++q) o[q] = (short)f2bf(acc[q]);
    *(bf16x8*)(out + (size_t)node * HID + lane * 8) = o;
}

// ---------------- dual MFMA GEMM: C = relu(A0@B0 + A1@B1 + bias) ----------------
// A: [MPAD][K] bf16; Bt: [512][K] bf16 (pre-transposed). 128x128 tile, BK=32,
// 4 waves (2x2 of 64x64), 4x4 16x16x32 frags/wave.
// 2-phase double-buffer (round-4 verified): STAGE(next) -> compute(cur) ->
// __syncthreads(). The compiler's vmcnt(0) drain before s_barrier lands after
// a full compute phase. NO hand vmcnt: counted-vmcnt graft on a 2-phase loop
// regressed (round 5: compiler re-drains vmcnt(0) before ds_reads anyway).
// LDS k-slot XOR-swizzle p = s ^ ((row>>1)&3) applied BOTH on the per-lane
// global source (linear gload_lds dest) and the ds_read index (rule #21) --
// verified: SQ_LDS_BANK_CONFLICT 5.1M -> 0.
// Bijective XCD chunk swizzle (T1/m204) -- verified: FETCH 163 -> 50 MB.

template <int K, bool POOL>
__global__ __launch_bounds__(256)
void k_mfma_dual(const unsigned short* __restrict__ A0, const unsigned short* __restrict__ B0t,
                 const unsigned short* __restrict__ A1, const unsigned short* __restrict__ B1t,
                 const float* __restrict__ bias,
                 unsigned short* __restrict__ C,
                 const int* __restrict__ batch, float* __restrict__ psum) {
    constexpr int KT = K / 32;       // K-tiles per matrix
    constexpr int NT = 2 * KT;       // total tiles (two matrices)
    __shared__ unsigned short As[2][128 * 32];
    __shared__ unsigned short Bs[2][128 * 32];
    int tid = threadIdx.x;
    int l = tid & 63, w = tid >> 6;
    int wr = w >> 1, wc = w & 1;

    // bijective XCD chunking: orig -> logical wgid, contiguous chunk per XCD
    int nwg = gridDim.x;
    int orig = blockIdx.x;
    int q = nwg >> 3, r = nwg & 7;
    int xcd = orig & 7, idx = orig >> 3;
    int wgid = (xcd < r ? xcd * (q + 1) : r * (q + 1) + (xcd - r) * q) + idx;
    int row0 = (wgid >> 2) * 128;
    int col0 = (wgid & 3) * 128;

    int lr = l & 15, hi = l >> 4;
    int pofs = (hi ^ ((lr >> 1) & 3)) * 8;   // swizzled k-slot offset (ushorts)

    // staging chunk geometry: chunk c in [0,512), r=c>>2, p=c&3,
    // global slot g = p ^ ((r>>1)&3); LDS dest linear at c*16 bytes.
    int c0 = tid, c1 = tid + 256;
    int r0 = c0 >> 2, g0 = (c0 & 3) ^ ((r0 >> 1) & 3);
    int r1 = c1 >> 2, g1 = (c1 & 3) ^ ((r1 >> 1) & 3);

    const unsigned short* Amat[2] = {A0, A1};
    const unsigned short* Bmat[2] = {B0t, B1t};

    auto stage = [&](int t, int buf) {
        int mat = t / KT;
        int k0 = (t - mat * KT) * 32;
        const unsigned short* A = Amat[mat];
        const unsigned short* Bt = Bmat[mat];
        gload_lds16(A + (size_t)(row0 + r0) * K + k0 + g0 * 8, &As[buf][c0 * 8]);
        gload_lds16(A + (size_t)(row0 + r1) * K + k0 + g1 * 8, &As[buf][c1 * 8]);
        gload_lds16(Bt + (size_t)(col0 + r0) * K + k0 + g0 * 8, &Bs[buf][c0 * 8]);
        gload_lds16(Bt + (size_t)(col0 + r1) * K + k0 + g1 * 8, &Bs[buf][c1 * 8]);
    };

    f32x4 acc[4][4];
#pragma unroll
    for (int m = 0; m < 4; ++m)
#pragma unroll
        for (int n = 0; n < 4; ++n) acc[m][n] = (f32x4)0.f;

    stage(0, 0);
    __syncthreads();

    int cur = 0;
    for (int t = 0; t < NT; ++t) {
        if (t + 1 < NT) stage(t + 1, cur ^ 1);
        const unsigned short* Ab = &As[cur][0];
        const unsigned short* Bb = &Bs[cur][0];
        bf16x8 af[4], bfr[4];
#pragma unroll
        for (int m = 0; m < 4; ++m)
            af[m] = *(const bf16x8*)&Ab[(wr * 64 + m * 16 + lr) * 32 + pofs];
#pragma unroll
        for (int n = 0; n < 4; ++n)
            bfr[n] = *(const bf16x8*)&Bb[(wc * 64 + n * 16 + lr) * 32 + pofs];
#pragma unroll
        for (int m = 0; m < 4; ++m)
#pragma unroll
            for (int n = 0; n < 4; ++n)
                acc[m][n] = __builtin_amdgcn_mfma_f32_16x16x32_bf16(af[m], bfr[n], acc[m][n], 0, 0, 0);
        __syncthreads();   // drains vmcnt (next tile staged) + protects buf reuse
        cur ^= 1;
    }

    // epilogue: C/D layout col = l&15, row = (l>>4)*4 + i
    float bv[4];
#pragma unroll
    for (int n = 0; n < 4; ++n) bv[n] = bias[col0 + wc * 64 + n * 16 + lr];
    int rbase = row0 + wr * 64 + hi * 4;

    if constexpr (!POOL) {
#pragma unroll
        for (int m = 0; m < 4; ++m) {
#pragma unroll
            for (int i = 0; i < 4; ++i) {
                int rr = rbase + m * 16 + i;
                if (rr < NNODES) {
#pragma unroll
                    for (int n = 0; n < 4; ++n) {
                        int col = col0 + wc * 64 + n * 16 + lr;
                        C[(size_t)rr * HID + col] = f2bf(fmaxf(acc[m][n][i] + bv[n], 0.f));
                    }
                }
            }
        }
    } else {
#pragma unroll
        for (int m = 0; m < 4; ++m) {
            int b[4];
#pragma unroll
            for (int i = 0; i < 4; ++i) {
                int rr = rbase + m * 16 + i;
                b[i] = (rr < NNODES) ? batch[rr] : -1;
            }
#pragma unroll
            for (int n = 0; n < 4; ++n) {
                int col = col0 + wc * 64 + n * 16 + lr;
                int cb = -1;
                float run = 0.f;
#pragma unroll
                for (int i = 0; i < 4; ++i) {
                    if (b[i] >= 0) {
                        float v = fmaxf(acc[m][n][i] + bv[n], 0.f);
                        if (b[i] == cb) {
                            run += v;
                        } else {
                            if (cb >= 0) atomicAdd(&psum[(size_t)cb * HID + col], run);
                            cb = b[i];
                            run = v;
                        }
                    }
                }
                if (cb >= 0) atomicAdd(&psum[(size_t)cb * HID + col], run);
            }
        }
    }
}

// ---------------- pooling count (LDS histogram) + MLP head (fp32) ----------------

__global__ void k_cnt(const int* __restrict__ batch, float* __restrict__ cnt) {
    __shared__ int h[NGRAPH];
    int t = threadIdx.x;
    if (t < NGRAPH) h[t] = 0;
    __syncthreads();
    int i = blockIdx.x * 256 + t;
    if (i < NNODES) atomicAdd(&h[batch[i]], 1);
    __syncthreads();
    if (t < NGRAPH && h[t] != 0) atomicAdd(&cnt[t], (float)h[t]);
}

__global__ void k_head(const float* __restrict__ psum, const float* __restrict__ cnt,
                       const float* __restrict__ W1, const float* __restrict__ b1,
                       const float* __restrict__ W2, const float* __restrict__ b2,
                       const float* __restrict__ W3, const float* __restrict__ b3,
                       float* __restrict__ out) {
    __shared__ float pooled[HID];
    __shared__ float o1[64];
    __shared__ float o2[16];
    int g = blockIdx.x, t = threadIdx.x;
    float c = fmaxf(cnt[g], 1.0f);
    for (int k = t; k < HID; k += 64) pooled[k] = psum[(size_t)g * HID + k] / c;
    __syncthreads();
    float a = b1[t];
    for (int k = 0; k < HID; ++k) a += pooled[k] * W1[k * 64 + t];
    o1[t] = fmaxf(a, 0.f);
    __syncthreads();
    if (t < 16) {
        float a2 = b2[t];
        for (int k = 0; k < 64; ++k) a2 += o1[k] * W2[k * 16 + t];
        o2[t] = fmaxf(a2, 0.f);
    }
    __syncthreads();
    if (t == 0) {
        float a3 = b3[0];
        for (int k = 0; k < 16; ++k) a3 += o2[k] * W3[k];
        out[g] = a3;
    }
}

// ---------------- launch ----------------

extern "C" void kernel_launch(void* const* d_in, const int* in_sizes, int n_in,
                              void* d_out, int out_size, void* d_ws, size_t ws_size,
                              hipStream_t stream) {
    const float* x = (const float*)d_in[0];
    const int* ei = (const int*)d_in[1];
    const int* src = ei;
    const int* dst = ei + NEDGES;
    const float* ew = (const float*)d_in[2];
    const int* batch = (const int*)d_in[3];
    const float* Wr1 = (const float*)d_in[4];
    const float* br1 = (const float*)d_in[5];
    const float* Wo1 = (const float*)d_in[6];
    const float* Wr2 = (const float*)d_in[7];
    const float* br2 = (const float*)d_in[8];
    const float* Wo2 = (const float*)d_in[9];
    const float* W1 = (const float*)d_in[10];
    const float* b1 = (const float*)d_in[11];
    const float* W2 = (const float*)d_in[12];
    const float* b2 = (const float*)d_in[13];
    const float* W3 = (const float*)d_in[14];
    const float* b3 = (const float*)d_in[15];
    float* out = (float*)d_out;

    char* ws = (char*)d_ws;
    size_t o = 0;
    auto alloc = [&](size_t bytes) -> void* {
        void* p = ws + o;
        o = (o + bytes + 255) & ~(size_t)255;
        return p;
    };
    int* deg = (int*)alloc((size_t)NNODES * 4);
    int* off = (int*)alloc((size_t)(NNODES + 1) * 4);
    int* cur = (int*)alloc((size_t)NNODES * 4);
    int* csrc = (int*)alloc((size_t)NEDGES * 4);
    float* cw = (float*)alloc((size_t)NEDGES * 4);
    unsigned short* xb = (unsigned short*)alloc((size_t)MPAD * FIN * 2);
    unsigned short* agg1 = (unsigned short*)alloc((size_t)MPAD * FIN * 2);
    unsigned short* h1 = (unsigned short*)alloc((size_t)MPAD * HID * 2);
    unsigned short* agg2 = (unsigned short*)alloc((size_t)MPAD * HID * 2);
    unsigned short* Wr1t = (unsigned short*)alloc((size_t)512 * FIN * 2);
    unsigned short* Wo1t = (unsigned short*)alloc((size_t)512 * FIN * 2);
    unsigned short* Wr2t = (unsigned short*)alloc((size_t)512 * HID * 2);
    unsigned short* Wo2t = (unsigned short*)alloc((size_t)512 * HID * 2);
    float* psum = (float*)alloc((size_t)NGRAPH * HID * 4);
    float* cnt = (float*)alloc((size_t)NGRAPH * 4);

    hipMemsetAsync(deg, 0, (size_t)NNODES * 4, stream);
    hipMemsetAsync(psum, 0, (size_t)NGRAPH * HID * 4, stream);
    hipMemsetAsync(cnt, 0, (size_t)NGRAPH * 4, stream);

    // conversions
    k_cvt_x<<<(MPAD * FIN / 8 + 255) / 256, 256, 0, stream>>>(x, xb);
    k_cvt_wt<<<(512 * FIN + 255) / 256, 256, 0, stream>>>(Wr1, Wr1t, FIN);
    k_cvt_wt<<<(512 * FIN + 255) / 256, 256, 0, stream>>>(Wo1, Wo1t, FIN);
    k_cvt_wt<<<(512 * HID + 255) / 256, 256, 0, stream>>>(Wr2, Wr2t, HID);
    k_cvt_wt<<<(512 * HID + 255) / 256, 256, 0, stream>>>(Wo2, Wo2t, HID);

    // CSR
    k_deg<<<(NEDGES + 255) / 256, 256, 0, stream>>>(dst, deg);
    k_scan<<<1, 1024, 0, stream>>>(deg, off, cur);
    k_fill<<<(NEDGES + 255) / 256, 256, 0, stream>>>(src, dst, ew, cur, csrc, cw);

    // layer 1
    k_agg128<<<(NNODES + 3) / 4, 256, 0, stream>>>(xb, off, csrc, cw, agg1);
    int nblk = (MPAD / 128) * 4;   // col in low 2 bits of logical id
    k_mfma_dual<FIN, false><<<nblk, 256, 0, stream>>>(agg1, Wr1t, xb, Wo1t, br1, h1, nullptr, nullptr);

    // layer 2 (+ fused mean-pool numerator)
    k_agg512<<<(NNODES + 3) / 4, 256, 0, stream>>>(h1, off, csrc, cw, agg2);
    k_cnt<<<(NNODES + 255) / 256, 256, 0, stream>>>(batch, cnt);
    k_mfma_dual<HID, true><<<nblk, 256, 0, stream>>>(agg2, Wr2t, h1, Wo2t, br2, nullptr, batch, psum);

    // head
    k_head<<<NGRAPH, 64, 0, stream>>>(psum, cnt, W1, b1, W2, b2, W3, b3, out);
}

// Round 7
// 477.038 us; speedup vs baseline: 1.1545x; 1.1381x over previous
//
#include <hip/hip_runtime.h>
#include <hip/hip_bf16.h>

#define NNODES 40000
#define MPAD   40192   // 157 * 256
#define NEDGES 640000
#define FIN    128
#define HID    512
#define NGRAPH 64

typedef __attribute__((ext_vector_type(8))) short bf16x8;
typedef __attribute__((ext_vector_type(4))) float f32x4;

__device__ __forceinline__ unsigned short f2bf(float f) {
    unsigned int u = __builtin_bit_cast(unsigned int, f);
    u += 0x7FFFu + ((u >> 16) & 1u);   // RNE
    return (unsigned short)(u >> 16);
}
__device__ __forceinline__ float bf2f(unsigned short s) {
    return __builtin_bit_cast(float, (unsigned int)s << 16);
}

__device__ __forceinline__ void gload_lds16(const void* g, void* l) {
    __builtin_amdgcn_global_load_lds(
        (const __attribute__((address_space(1))) void*)g,
        (__attribute__((address_space(3))) void*)l, 16, 0, 0);
}

// ---------------- conversions ----------------

__global__ void k_cvt_x(const float* __restrict__ x, unsigned short* __restrict__ xb) {
    size_t e = ((size_t)blockIdx.x * 256 + threadIdx.x) * 8;
    if (e >= (size_t)MPAD * FIN) return;
    bf16x8 o;
    if (e < (size_t)NNODES * FIN) {
        float4 v0 = *(const float4*)(x + e);
        float4 v1 = *(const float4*)(x + e + 4);
        o[0] = f2bf(v0.x); o[1] = f2bf(v0.y); o[2] = f2bf(v0.z); o[3] = f2bf(v0.w);
        o[4] = f2bf(v1.x); o[5] = f2bf(v1.y); o[6] = f2bf(v1.z); o[7] = f2bf(v1.w);
    } else {
        o = (bf16x8)0;
    }
    *(bf16x8*)(xb + e) = o;
}

__global__ void k_cvt_wt(const float* __restrict__ W, unsigned short* __restrict__ Wt, int K) {
    int t = blockIdx.x * 256 + threadIdx.x;
    if (t >= 512 * K) return;
    int n = t / K, k = t - n * K;
    Wt[t] = f2bf(W[(size_t)k * 512 + n]);
}

// ---------------- CSR build ----------------

__global__ void k_deg(const int* __restrict__ dst, int* __restrict__ deg) {
    int e = blockIdx.x * 256 + threadIdx.x;
    if (e < NEDGES) atomicAdd(&deg[dst[e]], 1);
}

__global__ void k_scan(const int* __restrict__ deg, int* __restrict__ off, int* __restrict__ cursor) {
    __shared__ int sh[1024];
    constexpr int CH = (NNODES + 1023) / 1024;
    int t = threadIdx.x;
    int base = t * CH;
    int vals[CH];
    int local = 0;
#pragma unroll
    for (int i = 0; i < CH; ++i) {
        int idx = base + i;
        int v = (idx < NNODES) ? deg[idx] : 0;
        vals[i] = v;
        local += v;
    }
    sh[t] = local;
    __syncthreads();
    for (int o = 1; o < 1024; o <<= 1) {
        int add = (t >= o) ? sh[t - o] : 0;
        __syncthreads();
        sh[t] += add;
        __syncthreads();
    }
    int run = sh[t] - local;
#pragma unroll
    for (int i = 0; i < CH; ++i) {
        int idx = base + i;
        if (idx < NNODES) {
            off[idx] = run;
            cursor[idx] = run;
            run += vals[i];
        }
    }
    if (t == 1023) off[NNODES] = sh[1023];
}

__global__ void k_fill(const int* __restrict__ src, const int* __restrict__ dst,
                       const float* __restrict__ ew, int* __restrict__ cursor,
                       int* __restrict__ csrc, float* __restrict__ cw) {
    int e = blockIdx.x * 256 + threadIdx.x;
    if (e < NEDGES) {
        int p = atomicAdd(&cursor[dst[e]], 1);
        csrc[p] = src[e];
        cw[p] = ew[e];
    }
}

// ---------------- aggregation (gather, bf16 in/out, fp32 accum) ----------------

__global__ void k_agg128(const unsigned short* __restrict__ xb, const int* __restrict__ off,
                         const int* __restrict__ csrc, const float* __restrict__ cw,
                         unsigned short* __restrict__ out) {
    int node = blockIdx.x * 4 + (threadIdx.x >> 6);
    if (node >= NNODES) return;
    int lane = threadIdx.x & 63;
    float a0 = 0.f, a1 = 0.f;
    int s = off[node], e = off[node + 1];
    for (int k = s; k < e; ++k) {
        int j = csrc[k];
        float w = cw[k];
        unsigned int v = *(const unsigned int*)(xb + (size_t)j * FIN + lane * 2);
        a0 += w * bf2f((unsigned short)(v & 0xFFFF));
        a1 += w * bf2f((unsigned short)(v >> 16));
    }
    unsigned int o = (unsigned int)f2bf(a0) | ((unsigned int)f2bf(a1) << 16);
    *(unsigned int*)(out + (size_t)node * FIN + lane * 2) = o;
}

__global__ void k_agg512(const unsigned short* __restrict__ h, const int* __restrict__ off,
                         const int* __restrict__ csrc, const float* __restrict__ cw,
                         unsigned short* __restrict__ out) {
    int node = blockIdx.x * 4 + (threadIdx.x >> 6);
    if (node >= NNODES) return;
    int lane = threadIdx.x & 63;
    float acc[8] = {};
    int s = off[node], e = off[node + 1];
    for (int k = s; k < e; ++k) {
        int j = csrc[k];
        float w = cw[k];
        bf16x8 a = *(const bf16x8*)(h + (size_t)j * HID + lane * 8);
#pragma unroll
        for (int q = 0; q < 8; ++q)
            acc[q] += w * bf2f((unsigned short)a[q]);
    }
    bf16x8 o;
#pragma unroll
    for (int q = 0; q < 8; ++q) o[q] = (short)f2bf(acc[q]);
    *(bf16x8*)(out + (size_t)node * HID + lane * 8) = o;
}

// ---------------- dual MFMA GEMM: C = relu(A0@B0 + A1@B1 + bias) ----------------
// 256x256 tile, BK=64, 512 threads = 8 waves (2M x 4N), wave tile 128x64,
// 8x4 16x16x32 frags/wave. LDS 128KB dbuf. Rationale (R6 post-mortem): the
// kernel is staging-throughput-bound; 256^2 cuts staged volume 3.2x vs 128^2.
// 2-phase verified loop: STAGE(next) -> compute(cur) -> __syncthreads().
// No XCD swizzle (R4 vs R6 A/B: swizzle cost +48% in this regime).
// XOR swizzle for 128B rows: slot' = slot ^ (row&7), applied BOTH on the
// per-lane global source (linear gload_lds dest) and the ds_read index.
// 16 lanes/quarter-wave -> 8 distinct slots x 2 lanes = 2-way = free (m136).

template <int K, bool POOL>
__global__ __launch_bounds__(512, 2)
void k_mfma_dual(const unsigned short* __restrict__ A0, const unsigned short* __restrict__ B0t,
                 const unsigned short* __restrict__ A1, const unsigned short* __restrict__ B1t,
                 const float* __restrict__ bias,
                 unsigned short* __restrict__ C,
                 const int* __restrict__ batch, float* __restrict__ psum) {
    constexpr int KT = K / 64;       // K-tiles per matrix
    constexpr int NT = 2 * KT;       // total tiles (two matrices)
    __shared__ unsigned short As[2][256 * 64];
    __shared__ unsigned short Bs[2][256 * 64];
    int tid = threadIdx.x;
    int l = tid & 63, w = tid >> 6;
    int wr = w >> 2, wc = w & 3;     // 2M x 4N waves, wave tile 128x64
    int bid = blockIdx.x;
    int row0 = (bid >> 1) * 256;
    int col0 = (bid & 1) * 256;

    int lr = l & 15, hi = l >> 4;

    const unsigned short* Amat[2] = {A0, A1};
    const unsigned short* Bmat[2] = {B0t, B1t};

    // staging: 2048 chunks of 16B per matrix; chunk c: row r=c>>3, slot p=c&7,
    // global slot g = p ^ (r&7); LDS dest linear at c*16B. 4 A + 4 B per thread.
    auto stage = [&](int t, int buf) {
        int mat = t / KT;
        int k0 = (t - mat * KT) * 64;
        const unsigned short* A = Amat[mat];
        const unsigned short* Bt = Bmat[mat];
#pragma unroll
        for (int qc = 0; qc < 4; ++qc) {
            int c = qc * 512 + tid;
            int r = c >> 3, g = (c & 7) ^ (r & 7);
            gload_lds16(A + (size_t)(row0 + r) * K + k0 + g * 8, &As[buf][c * 8]);
            gload_lds16(Bt + (size_t)(col0 + r) * K + k0 + g * 8, &Bs[buf][c * 8]);
        }
    };

    f32x4 acc[8][4];
#pragma unroll
    for (int m = 0; m < 8; ++m)
#pragma unroll
        for (int n = 0; n < 4; ++n) acc[m][n] = (f32x4)0.f;

    stage(0, 0);
    __syncthreads();

    int cur = 0;
    for (int t = 0; t < NT; ++t) {
        if (t + 1 < NT) stage(t + 1, cur ^ 1);
        const unsigned short* Ab = &As[cur][0];
        const unsigned short* Bb = &Bs[cur][0];
#pragma unroll
        for (int s = 0; s < 2; ++s) {
            int ps = ((s * 4 + hi) ^ (lr & 7)) * 8;   // swizzled k-slot (ushorts)
            bf16x8 af[8], bfr[4];
#pragma unroll
            for (int m = 0; m < 8; ++m)
                af[m] = *(const bf16x8*)&Ab[(wr * 128 + m * 16 + lr) * 64 + ps];
#pragma unroll
            for (int n = 0; n < 4; ++n)
                bfr[n] = *(const bf16x8*)&Bb[(wc * 64 + n * 16 + lr) * 64 + ps];
#pragma unroll
            for (int m = 0; m < 8; ++m)
#pragma unroll
                for (int n = 0; n < 4; ++n)
                    acc[m][n] = __builtin_amdgcn_mfma_f32_16x16x32_bf16(af[m], bfr[n], acc[m][n], 0, 0, 0);
        }
        __syncthreads();   // drains vmcnt (next tile staged) + protects buf reuse
        cur ^= 1;
    }

    // epilogue: C/D layout col = l&15, row = (l>>4)*4 + i
    float bv[4];
#pragma unroll
    for (int n = 0; n < 4; ++n) bv[n] = bias[col0 + wc * 64 + n * 16 + lr];
    int rbase = row0 + wr * 128 + hi * 4;

    if constexpr (!POOL) {
#pragma unroll
        for (int m = 0; m < 8; ++m) {
#pragma unroll
            for (int i = 0; i < 4; ++i) {
                int rr = rbase + m * 16 + i;
                if (rr < NNODES) {
#pragma unroll
                    for (int n = 0; n < 4; ++n) {
                        int col = col0 + wc * 64 + n * 16 + lr;
                        C[(size_t)rr * HID + col] = f2bf(fmaxf(acc[m][n][i] + bv[n], 0.f));
                    }
                }
            }
        }
    } else {
#pragma unroll
        for (int m = 0; m < 8; ++m) {
            int b[4];
#pragma unroll
            for (int i = 0; i < 4; ++i) {
                int rr = rbase + m * 16 + i;
                b[i] = (rr < NNODES) ? batch[rr] : -1;
            }
#pragma unroll
            for (int n = 0; n < 4; ++n) {
                int col = col0 + wc * 64 + n * 16 + lr;
                int cb = -1;
                float run = 0.f;
#pragma unroll
                for (int i = 0; i < 4; ++i) {
                    if (b[i] >= 0) {
                        float v = fmaxf(acc[m][n][i] + bv[n], 0.f);
                        if (b[i] == cb) {
                            run += v;
                        } else {
                            if (cb >= 0) atomicAdd(&psum[(size_t)cb * HID + col], run);
                            cb = b[i];
                            run = v;
                        }
                    }
                }
                if (cb >= 0) atomicAdd(&psum[(size_t)cb * HID + col], run);
            }
        }
    }
}

// ---------------- pooling count (LDS histogram) + MLP head (fp32) ----------------

__global__ void k_cnt(const int* __restrict__ batch, float* __restrict__ cnt) {
    __shared__ int h[NGRAPH];
    int t = threadIdx.x;
    if (t < NGRAPH) h[t] = 0;
    __syncthreads();
    int i = blockIdx.x * 256 + t;
    if (i < NNODES) atomicAdd(&h[batch[i]], 1);
    __syncthreads();
    if (t < NGRAPH && h[t] != 0) atomicAdd(&cnt[t], (float)h[t]);
}

__global__ void k_head(const float* __restrict__ psum, const float* __restrict__ cnt,
                       const float* __restrict__ W1, const float* __restrict__ b1,
                       const float* __restrict__ W2, const float* __restrict__ b2,
                       const float* __restrict__ W3, const float* __restrict__ b3,
                       float* __restrict__ out) {
    __shared__ float pooled[HID];
    __shared__ float o1[64];
    __shared__ float o2[16];
    int g = blockIdx.x, t = threadIdx.x;
    float c = fmaxf(cnt[g], 1.0f);
    for (int k = t; k < HID; k += 64) pooled[k] = psum[(size_t)g * HID + k] / c;
    __syncthreads();
    float a = b1[t];
    for (int k = 0; k < HID; ++k) a += pooled[k] * W1[k * 64 + t];
    o1[t] = fmaxf(a, 0.f);
    __syncthreads();
    if (t < 16) {
        float a2 = b2[t];
        for (int k = 0; k < 64; ++k) a2 += o1[k] * W2[k * 16 + t];
        o2[t] = fmaxf(a2, 0.f);
    }
    __syncthreads();
    if (t == 0) {
        float a3 = b3[0];
        for (int k = 0; k < 16; ++k) a3 += o2[k] * W3[k];
        out[g] = a3;
    }
}

// ---------------- launch ----------------

extern "C" void kernel_launch(void* const* d_in, const int* in_sizes, int n_in,
                              void* d_out, int out_size, void* d_ws, size_t ws_size,
                              hipStream_t stream) {
    const float* x = (const float*)d_in[0];
    const int* ei = (const int*)d_in[1];
    const int* src = ei;
    const int* dst = ei + NEDGES;
    const float* ew = (const float*)d_in[2];
    const int* batch = (const int*)d_in[3];
    const float* Wr1 = (const float*)d_in[4];
    const float* br1 = (const float*)d_in[5];
    const float* Wo1 = (const float*)d_in[6];
    const float* Wr2 = (const float*)d_in[7];
    const float* br2 = (const float*)d_in[8];
    const float* Wo2 = (const float*)d_in[9];
    const float* W1 = (const float*)d_in[10];
    const float* b1 = (const float*)d_in[11];
    const float* W2 = (const float*)d_in[12];
    const float* b2 = (const float*)d_in[13];
    const float* W3 = (const float*)d_in[14];
    const float* b3 = (const float*)d_in[15];
    float* out = (float*)d_out;

    char* ws = (char*)d_ws;
    size_t o = 0;
    auto alloc = [&](size_t bytes) -> void* {
        void* p = ws + o;
        o = (o + bytes + 255) & ~(size_t)255;
        return p;
    };
    int* deg = (int*)alloc((size_t)NNODES * 4);
    int* off = (int*)alloc((size_t)(NNODES + 1) * 4);
    int* cur = (int*)alloc((size_t)NNODES * 4);
    int* csrc = (int*)alloc((size_t)NEDGES * 4);
    float* cw = (float*)alloc((size_t)NEDGES * 4);
    unsigned short* xb = (unsigned short*)alloc((size_t)MPAD * FIN * 2);
    unsigned short* agg1 = (unsigned short*)alloc((size_t)MPAD * FIN * 2);
    unsigned short* h1 = (unsigned short*)alloc((size_t)MPAD * HID * 2);
    unsigned short* agg2 = (unsigned short*)alloc((size_t)MPAD * HID * 2);
    unsigned short* Wr1t = (unsigned short*)alloc((size_t)512 * FIN * 2);
    unsigned short* Wo1t = (unsigned short*)alloc((size_t)512 * FIN * 2);
    unsigned short* Wr2t = (unsigned short*)alloc((size_t)512 * HID * 2);
    unsigned short* Wo2t = (unsigned short*)alloc((size_t)512 * HID * 2);
    float* psum = (float*)alloc((size_t)NGRAPH * HID * 4);
    float* cnt = (float*)alloc((size_t)NGRAPH * 4);

    hipMemsetAsync(deg, 0, (size_t)NNODES * 4, stream);
    hipMemsetAsync(psum, 0, (size_t)NGRAPH * HID * 4, stream);
    hipMemsetAsync(cnt, 0, (size_t)NGRAPH * 4, stream);

    // conversions
    k_cvt_x<<<((MPAD * FIN / 8) + 255) / 256, 256, 0, stream>>>(x, xb);
    k_cvt_wt<<<(512 * FIN + 255) / 256, 256, 0, stream>>>(Wr1, Wr1t, FIN);
    k_cvt_wt<<<(512 * FIN + 255) / 256, 256, 0, stream>>>(Wo1, Wo1t, FIN);
    k_cvt_wt<<<(512 * HID + 255) / 256, 256, 0, stream>>>(Wr2, Wr2t, HID);
    k_cvt_wt<<<(512 * HID + 255) / 256, 256, 0, stream>>>(Wo2, Wo2t, HID);

    // CSR
    k_deg<<<(NEDGES + 255) / 256, 256, 0, stream>>>(dst, deg);
    k_scan<<<1, 1024, 0, stream>>>(deg, off, cur);
    k_fill<<<(NEDGES + 255) / 256, 256, 0, stream>>>(src, dst, ew, cur, csrc, cw);

    // layer 1
    k_agg128<<<(NNODES + 3) / 4, 256, 0, stream>>>(xb, off, csrc, cw, agg1);
    int nblk = (MPAD / 256) * 2;   // col in low bit of block id
    k_mfma_dual<FIN, false><<<nblk, 512, 0, stream>>>(agg1, Wr1t, xb, Wo1t, br1, h1, nullptr, nullptr);

    // layer 2 (+ fused mean-pool numerator)
    k_agg512<<<(NNODES + 3) / 4, 256, 0, stream>>>(h1, off, csrc, cw, agg2);
    k_cnt<<<(NNODES + 255) / 256, 256, 0, stream>>>(batch, cnt);
    k_mfma_dual<HID, true><<<nblk, 512, 0, stream>>>(agg2, Wr2t, h1, Wo2t, br2, nullptr, batch, psum);

    // head
    k_head<<<NGRAPH, 64, 0, stream>>>(psum, cnt, W1, b1, W2, b2, W3, b3, out);
}